// Round 4
// baseline (229.769 us; speedup 1.0000x reference)
//
#include <hip/hip_runtime.h>

typedef __attribute__((ext_vector_type(8))) short short8;
typedef __attribute__((ext_vector_type(4))) float f32x4;

// Problem constants (B, D, E, S, H, Z) = (16384, 512, 16, 1, 256, 256)
constexpr int Bsz = 16384;
constexpr int Dd  = 512;
constexpr int Ee  = 16;
constexpr int Hh  = 256;
constexpr int Zz  = 256;
constexpr int BT  = 64;      // rows per block
constexpr int WCLD = 17;     // wc padded stride (bank-conflict-free)
constexpr int SMEM_MAIN = 65536 + 2 * 32768 + 64 * WCLD * 4;  // hA + hidB[2] + wc = 135424 B

__device__ __forceinline__ unsigned short f2bf(float f) {
    unsigned u = __float_as_uint(f);
    u += 0x7FFFu + ((u >> 16) & 1u);          // round-to-nearest-even
    return (unsigned short)(u >> 16);
}

// Batched transpose + fp32->bf16: src [E][R][C] f32  ->  dst [E][C][R] bf16
__global__ void transpose_bf16(const float* __restrict__ src,
                               unsigned short* __restrict__ dst,
                               int R, int C) {
    __shared__ float tile[64][65];
    int tilesC = C >> 6, tilesR = R >> 6;
    int bid = blockIdx.x;
    int e  = bid / (tilesR * tilesC);
    int rm = bid % (tilesR * tilesC);
    int rt = rm / tilesC;
    int ct = rm % tilesC;
    int t  = threadIdx.x;
    int c  = t & 63;
    int r0 = t >> 6;
    const float* s = src + (size_t)e * R * C + (size_t)(rt * 64) * C + ct * 64;
    #pragma unroll
    for (int i = 0; i < 16; ++i) {
        int r = r0 + i * 4;
        tile[r][c] = s[(size_t)r * C + c];
    }
    __syncthreads();
    unsigned short* d = dst + (size_t)e * R * C + (size_t)(ct * 64) * R + rt * 64;
    #pragma unroll
    for (int i = 0; i < 16; ++i) {
        int r = r0 + i * 4;
        d[(size_t)r * R + c] = f2bf(tile[c][r]);
    }
}

// Fused SoftMoE. grid = B/64 = 256 blocks, block = 512 threads (8 waves)
__global__ __launch_bounds__(512) void moe_fused(
    const float* __restrict__ hptr,            // [B][512] f32
    const float* __restrict__ phi,             // [512][16] f32
    const float* __restrict__ b1,              // [16][256] f32
    const float* __restrict__ b2,              // [16][256] f32
    const unsigned short* __restrict__ w1t,    // [16][256(h)][512(d)] bf16
    const unsigned short* __restrict__ w2t,    // [16][256(z)][256(h)] bf16
    float* __restrict__ out)                   // [B][256] f32
{
    extern __shared__ char smem[];
    char*  hA    = smem;                          // [64][512] bf16 swizzled, 64KB
    char*  hidB0 = smem + 65536;                  // [64][256] bf16 swizzled, 32KB
    char*  hidB1 = smem + 65536 + 32768;          // 32KB
    float* wc    = (float*)(smem + 131072);       // [64][17] gate softmax

    const int t    = threadIdx.x;
    const int lane = t & 63;
    const int wv   = t >> 6;          // wave 0..7 owns cols [wv*32, wv*32+32)
    const int l15  = lane & 15;
    const int lg   = lane >> 4;       // 0..3
    const int b0   = blockIdx.x * BT;

    // triple-buffered weight registers: prefetch distance 2 macro-steps
    short8 bf0[4][2], bf1[4][2], bf2[4][2];

    auto loadW = [&](short8 (&dst)[4][2], const unsigned short* wbase, int ldk, int kBase) {
        #pragma unroll
        for (int c = 0; c < 4; ++c)
            #pragma unroll
            for (int n = 0; n < 2; ++n) {
                int col = wv * 32 + n * 16 + l15;
                int kl  = kBase + c * 32 + lg * 8;
                dst[c][n] = *reinterpret_cast<const short8*>(wbase + (size_t)col * ldk + kl);
            }
    };
    auto mfma4_hA = [&](short8 (&bw)[4][2], f32x4 (&acc)[4][2], int kBase) {
        #pragma unroll
        for (int c = 0; c < 4; ++c) {
            int kl = kBase + c * 32 + lg * 8;
            short8 af[4];
            #pragma unroll
            for (int m = 0; m < 4; ++m) {
                int row = m * 16 + l15;
                af[m] = *reinterpret_cast<const short8*>(
                    hA + (row << 10) + (((kl >> 3) ^ (row & 7)) << 4));
            }
            #pragma unroll
            for (int n = 0; n < 2; ++n)
                #pragma unroll
                for (int m = 0; m < 4; ++m)
                    acc[m][n] = __builtin_amdgcn_mfma_f32_16x16x32_bf16(
                        af[m], bw[c][n], acc[m][n], 0, 0, 0);
        }
    };
    auto mfma4_hid = [&](const char* hsrc, short8 (&bw)[4][2], f32x4 (&acc)[4][2], int kBase) {
        #pragma unroll
        for (int c = 0; c < 4; ++c) {
            int kl = kBase + c * 32 + lg * 8;
            short8 af[4];
            #pragma unroll
            for (int m = 0; m < 4; ++m) {
                int row = m * 16 + l15;
                af[m] = *reinterpret_cast<const short8*>(
                    hsrc + (row << 9) + (((kl >> 3) ^ (row & 7)) << 4));
            }
            #pragma unroll
            for (int n = 0; n < 2; ++n)
                #pragma unroll
                for (int m = 0; m < 4; ++m)
                    acc[m][n] = __builtin_amdgcn_mfma_f32_16x16x32_bf16(
                        af[m], bw[c][n], acc[m][n], 0, 0, 0);
        }
    };

    // earliest prefetch: expert-0 GEMM1 macro-0 (hides under staging+gating)
    loadW(bf0, w1t, Dd, 0);

    // ---- stage h tile -> bf16 swizzled LDS (nontemporal: don't evict weights) ----
    {
        const f32x4* hsrc = reinterpret_cast<const f32x4*>(hptr + (size_t)b0 * Dd);
        #pragma unroll
        for (int i = 0; i < 16; ++i) {
            int idx = t + i * 512;
            int row = idx >> 7;
            int kc  = idx & 127;
            int k   = kc << 2;
            f32x4 v = __builtin_nontemporal_load(&hsrc[(size_t)row * 128 + kc]);
            unsigned lo = (unsigned)f2bf(v.x) | ((unsigned)f2bf(v.y) << 16);
            unsigned hi = (unsigned)f2bf(v.z) | ((unsigned)f2bf(v.w) << 16);
            int byte = (row << 10) + (((k >> 3) ^ (row & 7)) << 4) + ((k & 7) << 1);
            *reinterpret_cast<uint2*>(hA + byte) = make_uint2(lo, hi);
        }
    }
    __syncthreads();

    // ---- gating via MFMA: all waves compute 64x16 logits, wave 0 stores ----
    {
        f32x4 g[4];
        #pragma unroll
        for (int m = 0; m < 4; ++m) g[m] = (f32x4){0.f, 0.f, 0.f, 0.f};
        #pragma unroll
        for (int kc = 0; kc < 16; ++kc) {
            int kb = kc * 32 + lg * 8;
            short8 bfr;
            #pragma unroll
            for (int j = 0; j < 8; ++j)
                bfr[j] = (short)f2bf(phi[(size_t)(kb + j) * Ee + l15]);
            #pragma unroll
            for (int m = 0; m < 4; ++m) {
                int row = m * 16 + l15;
                short8 af = *reinterpret_cast<const short8*>(
                    hA + (row << 10) + (((kb >> 3) ^ (row & 7)) << 4));
                g[m] = __builtin_amdgcn_mfma_f32_16x16x32_bf16(af, bfr, g[m], 0, 0, 0);
            }
        }
        if (wv == 0) {
            #pragma unroll
            for (int m = 0; m < 4; ++m)
                #pragma unroll
                for (int j = 0; j < 4; ++j)
                    wc[(m * 16 + lg * 4 + j) * WCLD + l15] = g[m][j];
        }
    }
    __syncthreads();
    if (t < 64) {
        float w[16];
        float mx = -1e30f;
        #pragma unroll
        for (int e = 0; e < 16; ++e) { w[e] = wc[t * WCLD + e]; mx = fmaxf(mx, w[e]); }
        float s = 0.f;
        #pragma unroll
        for (int e = 0; e < 16; ++e) { w[e] = __expf(w[e] - mx); s += w[e]; }
        float inv = 1.f / s;
        #pragma unroll
        for (int e = 0; e < 16; ++e) wc[t * WCLD + e] = w[e] * inv;
    }
    __syncthreads();

    // fill the distance-2 pipeline for expert 0
    loadW(bf1, w1t, Dd, 128);
    loadW(bf2, w1t, Dd, 256);

    const f32x4 zero4 = {0.f, 0.f, 0.f, 0.f};
    f32x4 outacc[4][2];
    #pragma unroll
    for (int m = 0; m < 4; ++m)
        #pragma unroll
        for (int n = 0; n < 2; ++n) outacc[m][n] = zero4;

    const unsigned short* w1e = w1t;
    for (int e = 0; e < Ee; ++e) {
        const unsigned short* w2e = w2t + (size_t)e * Zz * Hh;
        const unsigned short* w1n = w1t + (size_t)((e + 1) & 15) * Hh * Dd;
        char* hw = (e & 1) ? hidB1 : hidB0;

        f32x4 hacc[4][2];
        #pragma unroll
        for (int m = 0; m < 4; ++m)
            #pragma unroll
            for (int n = 0; n < 2; ++n) hacc[m][n] = zero4;

        // GEMM1: hid = h @ W1[e], K=512 as 4 macro-steps (use buf, refill 2 ahead)
        mfma4_hA(bf0, hacc, 0);    loadW(bf0, w1e, Dd, 384);
        mfma4_hA(bf1, hacc, 128);  loadW(bf1, w2e, Hh, 0);
        mfma4_hA(bf2, hacc, 256);  loadW(bf2, w2e, Hh, 128);
        mfma4_hA(bf0, hacc, 384);  loadW(bf0, w1n, Dd, 0);

        // epilogue1: +b1, relu, * c[row,e] -> bf16 hw (double-buffered)
        #pragma unroll
        for (int n = 0; n < 2; ++n) {
            int col = wv * 32 + n * 16 + l15;
            float bias = b1[(size_t)e * Hh + col];
            #pragma unroll
            for (int m = 0; m < 4; ++m) {
                #pragma unroll
                for (int j = 0; j < 4; ++j) {
                    int row = m * 16 + lg * 4 + j;
                    float v = fmaxf(hacc[m][n][j] + bias, 0.f) * wc[row * WCLD + e];
                    int byte = (row << 9) + (((col >> 3) ^ (row & 7)) << 4) + ((col & 7) << 1);
                    *reinterpret_cast<unsigned short*>(hw + byte) = f2bf(v);
                }
            }
        }
        // LDS-only barrier: drain ds_writes, keep weight prefetches in flight
        asm volatile("s_waitcnt lgkmcnt(0)\n\ts_barrier" ::: "memory");

        // GEMM2: out += hid' @ W2[e], K=256 as 2 macro-steps
        mfma4_hid(hw, bf1, outacc, 0);    loadW(bf1, w1n, Dd, 128);
        mfma4_hid(hw, bf2, outacc, 128);  loadW(bf2, w1n, Dd, 256);

        w1e = w1n;
    }

    // ---- final epilogue: out = outacc + sum_e c[row,e]*b2[e,:] ----
    float b2v[2][16];
    #pragma unroll
    for (int n = 0; n < 2; ++n) {
        int col = wv * 32 + n * 16 + l15;
        #pragma unroll
        for (int e = 0; e < 16; ++e) b2v[n][e] = b2[(size_t)e * Zz + col];
    }
    #pragma unroll
    for (int m = 0; m < 4; ++m) {
        #pragma unroll
        for (int j = 0; j < 4; ++j) {
            int row = m * 16 + lg * 4 + j;
            float wrow[16];
            #pragma unroll
            for (int e = 0; e < 16; ++e) wrow[e] = wc[row * WCLD + e];
            #pragma unroll
            for (int n = 0; n < 2; ++n) {
                int col = wv * 32 + n * 16 + l15;
                float v = outacc[m][n][j];
                #pragma unroll
                for (int e = 0; e < 16; ++e) v = fmaf(wrow[e], b2v[n][e], v);
                __builtin_nontemporal_store(v, &out[(size_t)(b0 + row) * Zz + col]);
            }
        }
    }
}

extern "C" void kernel_launch(void* const* d_in, const int* in_sizes, int n_in,
                              void* d_out, int out_size, void* d_ws, size_t ws_size,
                              hipStream_t stream) {
    const float* h   = (const float*)d_in[0];
    const float* phi = (const float*)d_in[1];
    const float* W1  = (const float*)d_in[2];
    const float* b1  = (const float*)d_in[3];
    const float* W2  = (const float*)d_in[4];
    const float* b2  = (const float*)d_in[5];
    float* out = (float*)d_out;

    unsigned short* w1t = (unsigned short*)d_ws;                      // 4 MB
    unsigned short* w2t = w1t + (size_t)Ee * Hh * Dd;                 // 2 MB

    (void)hipFuncSetAttribute((const void*)moe_fused,
                              hipFuncAttributeMaxDynamicSharedMemorySize, SMEM_MAIN);

    transpose_bf16<<<Ee * (Dd / 64) * (Hh / 64), 256, 0, stream>>>(W1, w1t, Dd, Hh);
    transpose_bf16<<<Ee * (Hh / 64) * (Zz / 64), 256, 0, stream>>>(W2, w2t, Hh, Zz);

    moe_fused<<<Bsz / BT, 512, SMEM_MAIN, stream>>>(h, phi, b1, b2, w1t, w2t, out);
}

// Round 5
// 212.270 us; speedup vs baseline: 1.0824x; 1.0824x over previous
//
#include <hip/hip_runtime.h>

typedef __attribute__((ext_vector_type(8))) short short8;
typedef __attribute__((ext_vector_type(4))) float f32x4;

// Problem constants (B, D, E, S, H, Z) = (16384, 512, 16, 1, 256, 256)
constexpr int Bsz = 16384;
constexpr int Dd  = 512;
constexpr int Ee  = 16;
constexpr int Hh  = 256;
constexpr int Zz  = 256;
constexpr int BT  = 64;       // rows per block
constexpr int WCLD = 17;      // wc padded stride
constexpr int HLD  = 544;     // hidB row stride bytes (512 + 32 pad: bank-spread)
constexpr int SMEM_MAIN = 65536 + 2 * (BT * HLD) + 64 * WCLD * 4;  // 139520 B

__device__ __forceinline__ unsigned short f2bf(float f) {
    unsigned u = __float_as_uint(f);
    u += 0x7FFFu + ((u >> 16) & 1u);          // round-to-nearest-even
    return (unsigned short)(u >> 16);
}

// Batched transpose + fp32->bf16: src [E][R][C] f32  ->  dst [E][C][R] bf16
__global__ void transpose_bf16(const float* __restrict__ src,
                               unsigned short* __restrict__ dst,
                               int R, int C) {
    __shared__ float tile[64][65];
    int tilesC = C >> 6, tilesR = R >> 6;
    int bid = blockIdx.x;
    int e  = bid / (tilesR * tilesC);
    int rm = bid % (tilesR * tilesC);
    int rt = rm / tilesC;
    int ct = rm % tilesC;
    int t  = threadIdx.x;
    int c  = t & 63;
    int r0 = t >> 6;
    const float* s = src + (size_t)e * R * C + (size_t)(rt * 64) * C + ct * 64;
    #pragma unroll
    for (int i = 0; i < 16; ++i) {
        int r = r0 + i * 4;
        tile[r][c] = s[(size_t)r * C + c];
    }
    __syncthreads();
    unsigned short* d = dst + (size_t)e * R * C + (size_t)(ct * 64) * R + rt * 64;
    #pragma unroll
    for (int i = 0; i < 16; ++i) {
        int r = r0 + i * 4;
        d[(size_t)r * R + c] = f2bf(tile[c][r]);
    }
}

// Fused SoftMoE, transposed-GEMM form: hidT[h][b], outT[z][b].
// grid = B/64 = 256 blocks, block = 512 threads (8 waves), 1 block/CU.
__global__ __launch_bounds__(512, 2) void moe_fused(
    const float* __restrict__ hptr,            // [B][512] f32
    const float* __restrict__ phi,             // [512][16] f32
    const float* __restrict__ b1,              // [16][256] f32
    const float* __restrict__ b2,              // [16][256] f32
    const unsigned short* __restrict__ w1t,    // [16][256(h)][512(d)] bf16
    const unsigned short* __restrict__ w2t,    // [16][256(z)][256(h)] bf16
    float* __restrict__ out)                   // [B][256] f32
{
    extern __shared__ char smem[];
    char*  hA    = smem;                          // [64][512] bf16, XOR-swizzled, 64KB
    char*  hidB0 = smem + 65536;                  // [64 b][256 h] bf16, stride 544B
    char*  hidB1 = smem + 65536 + BT * HLD;
    float* wc    = (float*)(smem + 65536 + 2 * BT * HLD);  // [64][17] softmax

    const int t    = threadIdx.x;
    const int lane = t & 63;
    const int wv   = t >> 6;          // wave 0..7: owns h/z rows [wv*32, wv*32+32)
    const int l15  = lane & 15;
    const int lg   = lane >> 4;       // 0..3
    const int b0   = blockIdx.x * BT;

    // triple-buffered weight A-frags (prefetch distance 2 macro-steps)
    short8 bf0[4][2], bf1[4][2], bf2[4][2];

    // weights are the MFMA *A* operand now: row = h (or z) = wv*32 + mi*16 + l15
    auto loadW = [&](short8 (&dst)[4][2], const unsigned short* wbase, int ldk, int kBase) {
        #pragma unroll
        for (int c = 0; c < 4; ++c)
            #pragma unroll
            for (int mi = 0; mi < 2; ++mi) {
                int row = wv * 32 + mi * 16 + l15;
                int kl  = kBase + c * 32 + lg * 8;
                dst[c][mi] = *reinterpret_cast<const short8*>(wbase + (size_t)row * ldk + kl);
            }
    };
    // GEMM1-T: acc[mi][ni] += W1T-frag x hA-frag   (D[h][b])
    auto mfmaT_hA = [&](short8 (&bw)[4][2], f32x4 (&acc)[2][4], int kBase) {
        #pragma unroll
        for (int c = 0; c < 4; ++c) {
            int kl = kBase + c * 32 + lg * 8;
            short8 bfr[4];
            #pragma unroll
            for (int n = 0; n < 4; ++n) {
                int b = n * 16 + l15;
                bfr[n] = *reinterpret_cast<const short8*>(
                    hA + (b << 10) + (((kl >> 3) ^ (b & 7)) << 4));
            }
            #pragma unroll
            for (int mi = 0; mi < 2; ++mi)
                #pragma unroll
                for (int n = 0; n < 4; ++n)
                    acc[mi][n] = __builtin_amdgcn_mfma_f32_16x16x32_bf16(
                        bw[c][mi], bfr[n], acc[mi][n], 0, 0, 0);
        }
    };
    // GEMM2-T: acc[mi][ni] += W2T-frag x hid-frag  (D[z][b])
    auto mfmaT_hid = [&](const char* hsrc, short8 (&bw)[4][2], f32x4 (&acc)[2][4], int kBase) {
        #pragma unroll
        for (int c = 0; c < 4; ++c) {
            int kl = kBase + c * 32 + lg * 8;
            short8 bfr[4];
            #pragma unroll
            for (int n = 0; n < 4; ++n) {
                int b = n * 16 + l15;
                bfr[n] = *reinterpret_cast<const short8*>(hsrc + b * HLD + kl * 2);
            }
            #pragma unroll
            for (int mi = 0; mi < 2; ++mi)
                #pragma unroll
                for (int n = 0; n < 4; ++n)
                    acc[mi][n] = __builtin_amdgcn_mfma_f32_16x16x32_bf16(
                        bw[c][mi], bfr[n], acc[mi][n], 0, 0, 0);
        }
    };

    // earliest prefetch: expert-0 GEMM1 macro-0 (hides under staging+gating)
    loadW(bf0, w1t, Dd, 0);

    // ---- stage h tile -> bf16 swizzled LDS ----
    {
        const f32x4* hsrc = reinterpret_cast<const f32x4*>(hptr + (size_t)b0 * Dd);
        #pragma unroll
        for (int i = 0; i < 16; ++i) {
            int idx = t + i * 512;
            int row = idx >> 7;
            int kc  = idx & 127;
            int k   = kc << 2;
            f32x4 v = hsrc[(size_t)row * 128 + kc];
            unsigned lo = (unsigned)f2bf(v.x) | ((unsigned)f2bf(v.y) << 16);
            unsigned hi = (unsigned)f2bf(v.z) | ((unsigned)f2bf(v.w) << 16);
            int byte = (row << 10) + (((k >> 3) ^ (row & 7)) << 4) + ((k & 7) << 1);
            *reinterpret_cast<uint2*>(hA + byte) = make_uint2(lo, hi);
        }
    }
    __syncthreads();

    // ---- gating via MFMA: 64x16 logits, wave 0 stores ----
    {
        f32x4 g[4];
        #pragma unroll
        for (int m = 0; m < 4; ++m) g[m] = (f32x4){0.f, 0.f, 0.f, 0.f};
        #pragma unroll
        for (int kc = 0; kc < 16; ++kc) {
            int kb = kc * 32 + lg * 8;
            short8 bfr;
            #pragma unroll
            for (int j = 0; j < 8; ++j)
                bfr[j] = (short)f2bf(phi[(size_t)(kb + j) * Ee + l15]);
            #pragma unroll
            for (int m = 0; m < 4; ++m) {
                int row = m * 16 + l15;
                short8 af = *reinterpret_cast<const short8*>(
                    hA + (row << 10) + (((kb >> 3) ^ (row & 7)) << 4));
                g[m] = __builtin_amdgcn_mfma_f32_16x16x32_bf16(af, bfr, g[m], 0, 0, 0);
            }
        }
        if (wv == 0) {
            #pragma unroll
            for (int m = 0; m < 4; ++m)
                #pragma unroll
                for (int j = 0; j < 4; ++j)
                    wc[(m * 16 + lg * 4 + j) * WCLD + l15] = g[m][j];
        }
    }
    __syncthreads();
    if (t < 64) {
        float w[16];
        float mx = -1e30f;
        #pragma unroll
        for (int e = 0; e < 16; ++e) { w[e] = wc[t * WCLD + e]; mx = fmaxf(mx, w[e]); }
        float s = 0.f;
        #pragma unroll
        for (int e = 0; e < 16; ++e) { w[e] = __expf(w[e] - mx); s += w[e]; }
        float inv = 1.f / s;
        #pragma unroll
        for (int e = 0; e < 16; ++e) wc[t * WCLD + e] = w[e] * inv;
    }
    __syncthreads();

    // fill the distance-2 pipeline for expert 0
    loadW(bf1, w1t, Dd, 128);
    loadW(bf2, w1t, Dd, 256);

    const f32x4 zero4 = {0.f, 0.f, 0.f, 0.f};
    f32x4 outacc[2][4];
    #pragma unroll
    for (int mi = 0; mi < 2; ++mi)
        #pragma unroll
        for (int n = 0; n < 4; ++n) outacc[mi][n] = zero4;

    const unsigned short* w1e = w1t;
    for (int e = 0; e < Ee; ++e) {
        const unsigned short* w2e = w2t + (size_t)e * Zz * Hh;
        const unsigned short* w1n = w1t + (size_t)((e + 1) & 15) * Hh * Dd;
        char* hw = (e & 1) ? hidB1 : hidB0;

        f32x4 hacc[2][4];
        #pragma unroll
        for (int mi = 0; mi < 2; ++mi)
            #pragma unroll
            for (int n = 0; n < 4; ++n) hacc[mi][n] = zero4;

        // GEMM1-T: hidT = W1T @ hT, K=512 as 4 macro-steps, dist-2 refill
        mfmaT_hA(bf0, hacc, 0);    loadW(bf0, w1e, Dd, 384);
        mfmaT_hA(bf1, hacc, 128);  loadW(bf1, w2e, Hh, 0);
        mfmaT_hA(bf2, hacc, 256);  loadW(bf2, w2e, Hh, 128);
        mfmaT_hA(bf0, hacc, 384);  loadW(bf0, w1n, Dd, 0);

        // epilogue1-T: v = relu(hid + b1)*c[b,e]; pack 4 h-contig bf16 -> ds_write_b64
        #pragma unroll
        for (int mi = 0; mi < 2; ++mi) {
            int hb = wv * 32 + mi * 16 + lg * 4;
            f32x4 b1v = *reinterpret_cast<const f32x4*>(b1 + (size_t)e * Hh + hb);
            #pragma unroll
            for (int n = 0; n < 4; ++n) {
                int b = n * 16 + l15;
                float cbe = wc[b * WCLD + e];
                float v0 = fmaxf(hacc[mi][n][0] + b1v[0], 0.f) * cbe;
                float v1 = fmaxf(hacc[mi][n][1] + b1v[1], 0.f) * cbe;
                float v2 = fmaxf(hacc[mi][n][2] + b1v[2], 0.f) * cbe;
                float v3 = fmaxf(hacc[mi][n][3] + b1v[3], 0.f) * cbe;
                unsigned lo = (unsigned)f2bf(v0) | ((unsigned)f2bf(v1) << 16);
                unsigned hi = (unsigned)f2bf(v2) | ((unsigned)f2bf(v3) << 16);
                *reinterpret_cast<uint2*>(hw + b * HLD + hb * 2) = make_uint2(lo, hi);
            }
        }
        // LDS-only barrier: drain ds_writes, keep weight prefetches in flight
        asm volatile("s_waitcnt lgkmcnt(0)\n\ts_barrier" ::: "memory");

        // GEMM2-T: outT += W2T @ hidT', K=256 as 2 macro-steps
        mfmaT_hid(hw, bf1, outacc, 0);    loadW(bf1, w1n, Dd, 128);
        mfmaT_hid(hw, bf2, outacc, 128);  loadW(bf2, w1n, Dd, 256);

        w1e = w1n;
    }

    // ---- final epilogue: out[b][z] = outT[z][b] + sum_e c[b,e]*b2[e,z] ----
    {
        f32x4 res[2][4];
        #pragma unroll
        for (int mi = 0; mi < 2; ++mi)
            #pragma unroll
            for (int n = 0; n < 4; ++n) res[mi][n] = outacc[mi][n];
        int zb0 = wv * 32 + lg * 4;          // mi=0 z-base
        int zb1 = zb0 + 16;                  // mi=1 z-base
        #pragma unroll
        for (int e = 0; e < 16; ++e) {
            f32x4 b2v0 = *reinterpret_cast<const f32x4*>(b2 + (size_t)e * Zz + zb0);
            f32x4 b2v1 = *reinterpret_cast<const f32x4*>(b2 + (size_t)e * Zz + zb1);
            #pragma unroll
            for (int n = 0; n < 4; ++n) {
                float cbe = wc[(n * 16 + l15) * WCLD + e];
                res[0][n] += cbe * b2v0;
                res[1][n] += cbe * b2v1;
            }
        }
        #pragma unroll
        for (int mi = 0; mi < 2; ++mi) {
            int zb = (mi == 0) ? zb0 : zb1;
            #pragma unroll
            for (int n = 0; n < 4; ++n) {
                int b = b0 + n * 16 + l15;
                *reinterpret_cast<f32x4*>(out + (size_t)b * Zz + zb) = res[mi][n];
            }
        }
    }
}

extern "C" void kernel_launch(void* const* d_in, const int* in_sizes, int n_in,
                              void* d_out, int out_size, void* d_ws, size_t ws_size,
                              hipStream_t stream) {
    const float* h   = (const float*)d_in[0];
    const float* phi = (const float*)d_in[1];
    const float* W1  = (const float*)d_in[2];
    const float* b1  = (const float*)d_in[3];
    const float* W2  = (const float*)d_in[4];
    const float* b2  = (const float*)d_in[5];
    float* out = (float*)d_out;

    unsigned short* w1t = (unsigned short*)d_ws;                      // 4 MB
    unsigned short* w2t = w1t + (size_t)Ee * Hh * Dd;                 // 2 MB

    (void)hipFuncSetAttribute((const void*)moe_fused,
                              hipFuncAttributeMaxDynamicSharedMemorySize, SMEM_MAIN);

    transpose_bf16<<<Ee * (Dd / 64) * (Hh / 64), 256, 0, stream>>>(W1, w1t, Dd, Hh);
    transpose_bf16<<<Ee * (Hh / 64) * (Zz / 64), 256, 0, stream>>>(W2, w2t, Hh, Zz);

    moe_fused<<<Bsz / BT, 512, SMEM_MAIN, stream>>>(h, phi, b1, b2, w1t, w2t, out);
}